// Round 2
// baseline (71198.425 us; speedup 1.0000x reference)
//
#include <hip/hip_runtime.h>
#include <stdint.h>

// LayerNorm-LSTM, T=1024 B=64 D=512 H=512, ALL fp32 I/O (per reference).
// Persistent kernel: 256 wgs x 512 threads, custom agent-scope grid barrier
// (2 per step). wg g owns gate cols [8g, 8g+8). Weights read directly from W
// via wave-uniform addresses (s_load). Row work (both LNs + activations +
// c/h update) is wg-local in wgs 0..63 (wg b = batch row b).
// x-part of the gate GEMM for step t+1 is computed during phase 2 of step t.

typedef unsigned int u32;

#define NBLK 256
#define NT   512   // 8 waves

__device__ __forceinline__ float sigm(float x){ return 1.f / (1.f + __expf(-x)); }
__device__ __forceinline__ float tanhp(float x){
  float e = __expf(-2.f * fabsf(x));
  float t = (1.f - e) / (1.f + e);
  return x < 0.f ? -t : t;
}

// sense-reversing grid barrier. bar[0]=count, bar[1]=generation.
// Entry: release fence (wbl2) by tid0. Spin: relaxed agent loads (sc1 -> read
// coherence point, no per-poll invalidate). Exit: one acquire fence (inv).
__device__ __forceinline__ void gbar(int* bar){
  __syncthreads();
  if (threadIdx.x == 0){
    __builtin_amdgcn_fence(__ATOMIC_RELEASE, "agent");
    int g = __hip_atomic_load(bar + 1, __ATOMIC_RELAXED, __HIP_MEMORY_SCOPE_AGENT);
    int old = __hip_atomic_fetch_add(bar, 1, __ATOMIC_RELAXED, __HIP_MEMORY_SCOPE_AGENT);
    if (old == NBLK - 1){
      __hip_atomic_store(bar, 0, __ATOMIC_RELAXED, __HIP_MEMORY_SCOPE_AGENT);
      __hip_atomic_store(bar + 1, g + 1, __ATOMIC_RELEASE, __HIP_MEMORY_SCOPE_AGENT);
    } else {
      while (__hip_atomic_load(bar + 1, __ATOMIC_RELAXED, __HIP_MEMORY_SCOPE_AGENT) == g)
        __builtin_amdgcn_s_sleep(1);
    }
    __builtin_amdgcn_fence(__ATOMIC_ACQUIRE, "agent");
  }
  __syncthreads();
}

// init hbuf ([k][b] fp32) and cws ([b][m] fp32) from h0/c0
__global__ void prep_kernel(const float* __restrict__ h0, const float* __restrict__ c0,
                            float* __restrict__ hbuf, float* __restrict__ cws)
{
  const int b = blockIdx.x;
  for (int m = threadIdx.x; m < 512; m += blockDim.x){
    hbuf[m * 64 + b] = h0[b * 512 + m];
    cws[b * 512 + m] = c0[b * 512 + m];
  }
}

__global__ __launch_bounds__(NT, 1) void lstm_main(
    const float* __restrict__ x,      // [1024][64][512]
    const float* __restrict__ W,      // [1024][2048]
    const float* __restrict__ bias,   // [2048]
    const float* __restrict__ lgg, const float* __restrict__ lgb,  // [2048]
    const float* __restrict__ lcg, const float* __restrict__ lcb,  // [512]
    float* __restrict__ pg,     // [256][64][8]  x-part partial gates (+bias)
    float* __restrict__ graw,   // [64][2048]    raw gates
    float* __restrict__ hbuf,   // [512][64]     h state, [k][b]
    float* __restrict__ cws,    // [64][512]     c state
    int* bar,
    float* __restrict__ out)    // [1024][64][512] ++ h_last[64][512] ++ c_last[64][512]
{
  __shared__ float red[3584];   // 7 waves x 64 lanes x 8
  __shared__ float st[16];      // LN stats: 8 waves x {sum, sumsq}
  const int tid = threadIdx.x, g = blockIdx.x;
  const int wave = __builtin_amdgcn_readfirstlane(tid >> 6);
  const int lane = tid & 63;

  float biasr[8];
  #pragma unroll
  for (int j = 0; j < 8; j++) biasr[j] = bias[g * 8 + j];

  float vgg[4], vgb[4], vcg = 0.f, vcb = 0.f;
  if (g < 64){
    #pragma unroll
    for (int r = 0; r < 4; r++){ vgg[r] = lgg[r * 512 + tid]; vgb[r] = lgb[r * 512 + tid]; }
    vcg = lcg[tid]; vcb = lcb[tid];
  }

  const int k0 = wave * 64;

  // ---------- x-part GEMM for time tx -> pg[g][b][8] (+bias) ----------
  auto xgemm = [&](int tx){
    const float* xs = x + (size_t)tx * 32768;          // [64][512]
    float a[8] = {0,0,0,0,0,0,0,0};
    const float4* xb = (const float4*)(xs + lane * 512 + k0);   // 16 float4/lane
    #pragma unroll 4
    for (int i = 0; i < 16; i++){
      float4 v = xb[i];
      const float* wr = W + (size_t)(k0 + i * 4) * 2048 + g * 8;  // wave-uniform
      float xv[4] = {v.x, v.y, v.z, v.w};
      #pragma unroll
      for (int q = 0; q < 4; q++){
        const float* wq = wr + q * 2048;
        #pragma unroll
        for (int j = 0; j < 8; j++) a[j] = fmaf(xv[q], wq[j], a[j]);
      }
    }
    if (wave > 0){
      float4* dst = (float4*)(red + ((wave - 1) * 64 + lane) * 8);
      dst[0] = make_float4(a[0], a[1], a[2], a[3]);
      dst[1] = make_float4(a[4], a[5], a[6], a[7]);
    }
    __syncthreads();
    if (wave == 0){
      #pragma unroll
      for (int w = 0; w < 7; w++){
        const float* p = red + (w * 64 + lane) * 8;
        #pragma unroll
        for (int j = 0; j < 8; j++) a[j] += p[j];
      }
      float4* pgw = (float4*)(pg + g * 512 + lane * 8);
      pgw[0] = make_float4(a[0] + biasr[0], a[1] + biasr[1], a[2] + biasr[2], a[3] + biasr[3]);
      pgw[1] = make_float4(a[4] + biasr[4], a[5] + biasr[5], a[6] + biasr[6], a[7] + biasr[7]);
    }
  };

  xgemm(0);
  gbar(bar);

  for (int t = 0; t < 1024; t++){
    // ---- phase 1: h-part GEMM (W rows 512..1023) + pg -> graw ----
    {
      float a[8] = {0,0,0,0,0,0,0,0};
      const float* hb = hbuf + k0 * 64 + lane;   // lane = b, coalesced
      #pragma unroll 8
      for (int i = 0; i < 64; i++){
        float hv = hb[i * 64];
        const float* wr = W + (size_t)(512 + k0 + i) * 2048 + g * 8;  // wave-uniform
        #pragma unroll
        for (int j = 0; j < 8; j++) a[j] = fmaf(hv, wr[j], a[j]);
      }
      if (wave > 0){
        float4* dst = (float4*)(red + ((wave - 1) * 64 + lane) * 8);
        dst[0] = make_float4(a[0], a[1], a[2], a[3]);
        dst[1] = make_float4(a[4], a[5], a[6], a[7]);
      }
      __syncthreads();
      if (wave == 0){
        #pragma unroll
        for (int w = 0; w < 7; w++){
          const float* p = red + (w * 64 + lane) * 8;
          #pragma unroll
          for (int j = 0; j < 8; j++) a[j] += p[j];
        }
        const float* pgr = pg + g * 512 + lane * 8;
        float* gw = graw + lane * 2048 + g * 8;   // lane = b
        #pragma unroll
        for (int j = 0; j < 8; j++) gw[j] = a[j] + pgr[j];
      }
    }
    gbar(bar);

    // ---- phase 2: x-GEMM for t+1 (all wgs) + row work (wgs 0..63) ----
    if (t < 1023) xgemm(t + 1);

    if (g < 64){
      const int b = g;
      float gv[4];
      #pragma unroll
      for (int r = 0; r < 4; r++) gv[r] = graw[b * 2048 + r * 512 + tid];
      float s = 0.f, q = 0.f;
      #pragma unroll
      for (int r = 0; r < 4; r++){ s += gv[r]; q += gv[r] * gv[r]; }
      #pragma unroll
      for (int off = 32; off > 0; off >>= 1){ s += __shfl_xor(s, off, 64); q += __shfl_xor(q, off, 64); }
      if (lane == 0){ st[wave * 2] = s; st[wave * 2 + 1] = q; }
      __syncthreads();
      s = 0.f; q = 0.f;
      #pragma unroll
      for (int w = 0; w < 8; w++){ s += st[w * 2]; q += st[w * 2 + 1]; }
      float mu = s * (1.f / 2048.f);
      float rstd = rsqrtf(fmaxf(q * (1.f / 2048.f) - mu * mu, 0.f) + 1e-5f);
      float n[4];
      #pragma unroll
      for (int r = 0; r < 4; r++) n[r] = (gv[r] - mu) * rstd * vgg[r] + vgb[r];
      // thread tid handles gate index m = tid; f/i/g/o = n[0..3]
      float fv = sigm(n[0]), iv = sigm(n[1]), gg = tanhp(n[2]), ov = sigm(n[3]);
      float cv = cws[b * 512 + tid];
      float cr = fv * cv + iv * gg;
      float s2 = cr, q2 = cr * cr;
      #pragma unroll
      for (int off = 32; off > 0; off >>= 1){ s2 += __shfl_xor(s2, off, 64); q2 += __shfl_xor(q2, off, 64); }
      __syncthreads();                              // st reuse
      if (lane == 0){ st[wave * 2] = s2; st[wave * 2 + 1] = q2; }
      __syncthreads();
      s2 = 0.f; q2 = 0.f;
      #pragma unroll
      for (int w = 0; w < 8; w++){ s2 += st[w * 2]; q2 += st[w * 2 + 1]; }
      float mu2 = s2 * (1.f / 512.f);
      float rs2 = rsqrtf(fmaxf(q2 * (1.f / 512.f) - mu2 * mu2, 0.f) + 1e-5f);
      float cn = (cr - mu2) * rs2 * vcg + vcb;
      cws[b * 512 + tid] = cn;
      float hv = ov * tanhp(cn);
      out[(size_t)(t * 64 + b) * 512 + tid] = hv;
      hbuf[tid * 64 + b] = hv;                      // [k][b] for next step
      if (t == 1023){
        out[(size_t)33554432 + b * 512 + tid] = hv;            // h_last
        out[(size_t)33554432 + 32768 + b * 512 + tid] = cn;    // c_last
      }
    }
    if (t < 1023) gbar(bar);
  }
}

extern "C" void kernel_launch(void* const* d_in, const int* in_sizes, int n_in,
                              void* d_out, int out_size, void* d_ws, size_t ws_size,
                              hipStream_t stream){
  const float* x    = (const float*)d_in[0];
  const float* h0   = (const float*)d_in[1];
  const float* c0   = (const float*)d_in[2];
  const float* W    = (const float*)d_in[3];
  const float* bias = (const float*)d_in[4];
  const float* lgg  = (const float*)d_in[5];
  const float* lgb  = (const float*)d_in[6];
  const float* lcg  = (const float*)d_in[7];
  const float* lcb  = (const float*)d_in[8];
  float* out = (float*)d_out;

  char* ws = (char*)d_ws;
  int*   bar  = (int*)ws;                           // 4 KB reserved
  float* pg   = (float*)(ws + 4096);                // 512 KB
  float* graw = (float*)(ws + 4096 + 524288);       // 512 KB
  float* hbuf = (float*)(ws + 4096 + 1048576);      // 128 KB
  float* cws  = (float*)(ws + 4096 + 1179648);      // 128 KB
  // total ws use ~1.3 MB

  hipMemsetAsync(bar, 0, 256, stream);
  prep_kernel<<<64, 256, 0, stream>>>(h0, c0, hbuf, cws);
  lstm_main<<<NBLK, NT, 0, stream>>>(x, W, bias, lgg, lgb, lcg, lcb,
                                     pg, graw, hbuf, cws, bar, out);
}